// Round 9
// baseline (164.881 us; speedup 1.0000x reference)
//
#include <hip/hip_runtime.h>
#include <hip/hip_bf16.h>

#define DIN 128
#define DOUT 64
#define BROWS 256          // destination rows per bucket (bucket = row >> 8)
#define MAXBKT 512         // bucket counter array (nbuckets = 391)
#define NGEMM 391          // gemm-role blocks in fused kernel
#define NHIST 64           // hist-role blocks in fused kernel
#define PART_BLOCK 512
#define PART_VPT 8
#define PART_CHUNK (PART_BLOCK * PART_VPT)   // 4096 edges per partition block
#define CAP 3584           // LDS edge-list capacity per bucket (mean 2560, +20 sigma)
#define ACC_VPT 4          // register-held edges per thread in accum
#define WSTRIDE 136        // 128 + 8 pad ushorts: b128 reads 2-way-conflict-free

typedef short short8 __attribute__((ext_vector_type(8)));
typedef float f32x4 __attribute__((ext_vector_type(4)));

union U4S8 { uint4 u; short8 s; };
union BF2U { __hip_bfloat162 h; unsigned int u; };

__device__ inline unsigned int f2bf(float f) {
    union { float f; unsigned int u; } v; v.f = f;
    unsigned int u = v.u;
    u += 0x7fffu + ((u >> 16) & 1u);   // RNE
    return u >> 16;
}

// ---------------- fused: GEMM (blocks 0..NGEMM-1) + bucket hist/scan (rest) ----------------
// __launch_bounds__(512, 2): 2 waves/SIMD min -> up to ~256 VGPRs so wf/fv/af/acc
// stay in registers (R8's implicit bound gave 48 VGPRs -> spill-serialized loads).
__global__ __launch_bounds__(512, 2) void gemm_hist_kernel(const float* __restrict__ x,
                                                           const float* __restrict__ w,
                                                           unsigned short* __restrict__ support,
                                                           int ntiles,
                                                           const int* __restrict__ rows,
                                                           int* __restrict__ cnt,
                                                           int* __restrict__ base,
                                                           int* __restrict__ cursor,
                                                           int* __restrict__ done,
                                                           int E, int nb) {
    int tid = threadIdx.x;
    if (blockIdx.x < NGEMM) {
        // ---- GEMM role: support = bf16(x @ W), W staged fp32->bf16 into LDS ----
        __shared__ unsigned short wlds[DOUT * WSTRIDE];
        for (int i = tid; i < DIN * DOUT; i += 512) {
            int k = i >> 6, n = i & 63;            // w[k*64+n], coalesced read
            wlds[n * WSTRIDE + k] = (unsigned short)f2bf(w[i]);
        }
        __syncthreads();

        int lane = tid & 63, quad = lane >> 4, mlo = lane & 15;
        U4S8 wf[16];   // wf[kt*4+nt] = W[kt*32+quad*8 .. +8][nt*16+mlo]
#pragma unroll
        for (int kt = 0; kt < 4; ++kt)
#pragma unroll
            for (int nt = 0; nt < 4; ++nt)
                wf[kt * 4 + nt].u = *((const uint4*)(wlds + (nt * 16 + mlo) * WSTRIDE + kt * 32 + quad * 8));

        int wave0 = (blockIdx.x * 512 + tid) >> 6;
        int nwaves = NGEMM * 8;

        for (int tile = wave0; tile < ntiles; tile += nwaves) {
            const float4* p = (const float4*)(x + ((size_t)tile * 16 + mlo) * DIN + quad * 8);
            float4 fv[8];
#pragma unroll
            for (int kt = 0; kt < 4; ++kt) {
                fv[2 * kt]     = p[kt * 8];
                fv[2 * kt + 1] = p[kt * 8 + 1];
            }
            U4S8 af[4];
#pragma unroll
            for (int kt = 0; kt < 4; ++kt) {
                float4 a = fv[2 * kt], b = fv[2 * kt + 1];
                BF2U u0, u1, u2, u3;
                u0.h = __float22bfloat162_rn(make_float2(a.x, a.y));
                u1.h = __float22bfloat162_rn(make_float2(a.z, a.w));
                u2.h = __float22bfloat162_rn(make_float2(b.x, b.y));
                u3.h = __float22bfloat162_rn(make_float2(b.z, b.w));
                uint4 u; u.x = u0.u; u.y = u1.u; u.z = u2.u; u.w = u3.u;
                af[kt].u = u;
            }

            f32x4 acc[4] = {};
#pragma unroll
            for (int nt = 0; nt < 4; ++nt)
#pragma unroll
                for (int kt = 0; kt < 4; ++kt)
                    acc[nt] = __builtin_amdgcn_mfma_f32_16x16x32_bf16(af[kt].s, wf[kt * 4 + nt].s, acc[nt], 0, 0, 0);

#pragma unroll
            for (int nt = 0; nt < 4; ++nt)
#pragma unroll
                for (int r = 0; r < 4; ++r)
                    support[((size_t)tile * 16 + quad * 4 + r) * DOUT + nt * 16 + mlo] =
                        (unsigned short)f2bf(acc[nt][r]);
        }
    } else {
        // ---- HIST role: LDS-reduced bucket histogram + last-block scan ----
        __shared__ int c[MAXBKT];
        __shared__ int ticket;
        c[tid] = 0;
        __syncthreads();
        int bh = blockIdx.x - NGEMM;
        for (int e = bh * 512 + tid; e < E; e += NHIST * 512)
            atomicAdd(&c[rows[e] >> 8], 1);
        __syncthreads();
        int v = c[tid];
        if (v) atomicAdd(&cnt[tid], v);
        __syncthreads();              // all threads' global adds issued before ticket
        __threadfence();              // make them visible device-wide
        if (tid == 0) ticket = atomicAdd(done, 1);
        __syncthreads();
        if (ticket != NHIST - 1) return;
        if (tid >= 64) return;
        // last-done block: one-wave exclusive scan of bucket counts
        int lane = tid;
        int run = 0;
        for (int i0 = 0; i0 < nb; i0 += 64) {
            int cv = (i0 + lane < nb)
                         ? __hip_atomic_load(&cnt[i0 + lane], __ATOMIC_RELAXED, __HIP_MEMORY_SCOPE_AGENT)
                         : 0;
            int incl = cv;
            for (int o = 1; o < 64; o <<= 1) {
                int t = __shfl_up(incl, o);
                if (lane >= o) incl += t;
            }
            if (i0 + lane < nb) {
                base[i0 + lane]   = run + incl - cv;
                cursor[i0 + lane] = run + incl - cv;
            }
            run += __shfl(incl, 63);
        }
        if (lane == 0) base[nb] = run;
    }
}

// ---------------- partition edges into 256-row buckets ----------------
// tmp[d] = ( (row&255)<<17 | col , bits(val) ), bucket-contiguous.
__global__ __launch_bounds__(PART_BLOCK) void partition_kernel(const int* __restrict__ rows,
                                                               const int* __restrict__ cols,
                                                               const float* __restrict__ vals,
                                                               int* __restrict__ bucket_cursor,
                                                               uint2* __restrict__ tmp, int E) {
    __shared__ int cnt[MAXBKT];
    __shared__ int off[MAXBKT];
    __shared__ int gbase[MAXBKT];
    __shared__ int wsum[PART_BLOCK / 64];
    __shared__ int lkey[PART_CHUNK];
    __shared__ int lval[PART_CHUNK];
    __shared__ short lbkt[PART_CHUNK];

    int tid = threadIdx.x;
    int base = blockIdx.x * PART_CHUNK;

    cnt[tid] = 0;   // PART_BLOCK == MAXBKT == 512
    __syncthreads();

    int myr[PART_VPT], myc[PART_VPT], myrank[PART_VPT];
    float myv[PART_VPT];
#pragma unroll
    for (int i = 0; i < PART_VPT; ++i) {
        int e = base + i * PART_BLOCK + tid;
        if (e < E) {
            myr[i] = rows[e];
            myc[i] = cols[e];
            myv[i] = vals[e];
            myrank[i] = atomicAdd(&cnt[myr[i] >> 8], 1);
        }
    }
    __syncthreads();

    int c0 = cnt[tid];
    int lane = tid & 63, wid = tid >> 6;
    int ts = c0;
    for (int o = 1; o < 64; o <<= 1) {
        int t = __shfl_up(ts, o);
        if (lane >= o) ts += t;
    }
    if (lane == 63) wsum[wid] = ts;
    __syncthreads();
    int wb = 0;
    for (int w = 0; w < wid; ++w) wb += wsum[w];
    off[tid] = wb + ts - c0;                       // exclusive offsets within chunk
    if (c0 > 0) gbase[tid] = atomicAdd(&bucket_cursor[tid], c0);
    __syncthreads();

    int total = off[MAXBKT - 1] + cnt[MAXBKT - 1];

#pragma unroll
    for (int i = 0; i < PART_VPT; ++i) {
        int e = base + i * PART_BLOCK + tid;
        if (e < E) {
            int b = myr[i] >> 8;
            int pos = off[b] + myrank[i];
            lkey[pos] = ((myr[i] & (BROWS - 1)) << 17) | myc[i];
            lval[pos] = __float_as_int(myv[i]);
            lbkt[pos] = (short)b;
        }
    }
    __syncthreads();

    for (int s = tid; s < total; s += PART_BLOCK) {
        int b = lbkt[s];
        int d = gbase[b] + (s - off[b]);
        tmp[d] = make_uint2((unsigned)lkey[s], (unsigned)lval[s]);
    }
}

// ---------------- fused: single-pass in-LDS row-sort + split-wave pull ----------------
__global__ __launch_bounds__(1024) void accum_kernel(const int* __restrict__ bucket_base,
                                                     const uint2* __restrict__ tmp,
                                                     const unsigned short* __restrict__ support,
                                                     const float* __restrict__ bias,
                                                     float* __restrict__ out, int N) {
    __shared__ int cnt[BROWS];
    __shared__ int rstart[BROWS];
    __shared__ int cur[BROWS];
    __shared__ int wsum4[4];
    __shared__ uint2 list[CAP];    // 28 KB row-sorted (col,val) list

    int b = blockIdx.x;
    int rbase = b * BROWS;
    int nrows = min(BROWS, N - rbase);
    int tid = threadIdx.x, lane = tid & 63, wv = tid >> 6;   // 16 waves
    int start = bucket_base[b], end = bucket_base[b + 1];

    if (tid < BROWS) cnt[tid] = 0;
    __syncthreads();

    // count phase: hold edges in registers, fire-and-forget int LDS adds
    uint2 kv[ACC_VPT];
#pragma unroll
    for (int i = 0; i < ACC_VPT; ++i) {
        int s = start + i * 1024 + tid;
        if (s < end) {
            kv[i] = tmp[s];
            atomicAdd(&cnt[kv[i].x >> 17], 1);
        }
    }
    for (int s = start + ACC_VPT * 1024 + tid; s < end; s += 1024)
        atomicAdd(&cnt[tmp[s].x >> 17], 1);
    __syncthreads();

    // block scan of 256 counts (first 4 waves)
    int v = 0, incl = 0;
    if (tid < BROWS) {
        v = cnt[tid]; incl = v;
        for (int o = 1; o < 64; o <<= 1) {
            int t = __shfl_up(incl, o);
            if (lane >= o) incl += t;
        }
        if (lane == 63) wsum4[wv] = incl;
    }
    __syncthreads();
    if (tid < BROWS) {
        int wb = 0;
        for (int w = 0; w < wv; ++w) wb += wsum4[w];
        int st = wb + incl - v;
        rstart[tid] = st;
        cur[tid] = st;
    }
    __syncthreads();

    // place phase: from registers (cursor int RTN atomics)
#pragma unroll
    for (int i = 0; i < ACC_VPT; ++i) {
        int s = start + i * 1024 + tid;
        if (s < end) {
            int p = atomicAdd(&cur[kv[i].x >> 17], 1);
            if (p < CAP) list[p] = kv[i];
        }
    }
    for (int s = start + ACC_VPT * 1024 + tid; s < end; s += 1024) {
        uint2 k2 = tmp[s];
        int p = atomicAdd(&cur[k2.x >> 17], 1);
        if (p < CAP) list[p] = k2;
    }
    __syncthreads();

    // pull: half-wave = one row, lane covers 2 cols (dword bf16x2 gathers), unroll 4
    int half = lane >> 5, cl = lane & 31;
    float2 bl = ((const float2*)bias)[cl];
    for (int rp = wv * 2 + half; rp < nrows; rp += 32) {
        int s = min(rstart[rp], CAP);
        int e2 = min(s + cnt[rp], CAP);
        float a0 = 0.f, a1 = 0.f, c0 = 0.f, c1 = 0.f;
        for (; s + 4 <= e2; s += 4) {
            uint2 ea = list[s], eb = list[s + 1], ec = list[s + 2], ed = list[s + 3];
            unsigned ga = *((const unsigned*)(support + (size_t)(ea.x & 0x1FFFF) * DOUT) + cl);
            unsigned gb = *((const unsigned*)(support + (size_t)(eb.x & 0x1FFFF) * DOUT) + cl);
            unsigned gc = *((const unsigned*)(support + (size_t)(ec.x & 0x1FFFF) * DOUT) + cl);
            unsigned gd = *((const unsigned*)(support + (size_t)(ed.x & 0x1FFFF) * DOUT) + cl);
            float va = __uint_as_float(ea.y), vb = __uint_as_float(eb.y);
            float vc = __uint_as_float(ec.y), vd = __uint_as_float(ed.y);
            a0 = fmaf(va, __uint_as_float(ga << 16), a0);
            a1 = fmaf(va, __uint_as_float(ga & 0xffff0000u), a1);
            c0 = fmaf(vb, __uint_as_float(gb << 16), c0);
            c1 = fmaf(vb, __uint_as_float(gb & 0xffff0000u), c1);
            a0 = fmaf(vc, __uint_as_float(gc << 16), a0);
            a1 = fmaf(vc, __uint_as_float(gc & 0xffff0000u), a1);
            c0 = fmaf(vd, __uint_as_float(gd << 16), c0);
            c1 = fmaf(vd, __uint_as_float(gd & 0xffff0000u), c1);
        }
        for (; s < e2; ++s) {
            uint2 ea = list[s];
            unsigned ga = *((const unsigned*)(support + (size_t)(ea.x & 0x1FFFF) * DOUT) + cl);
            float va = __uint_as_float(ea.y);
            a0 = fmaf(va, __uint_as_float(ga << 16), a0);
            a1 = fmaf(va, __uint_as_float(ga & 0xffff0000u), a1);
        }
        float2 o;
        o.x = a0 + c0 + bl.x;
        o.y = a1 + c1 + bl.y;
        *((float2*)(out + (size_t)(rbase + rp) * DOUT) + cl) = o;
    }
}

extern "C" void kernel_launch(void* const* d_in, const int* in_sizes, int n_in,
                              void* d_out, int out_size, void* d_ws, size_t ws_size,
                              hipStream_t stream) {
    const float* x    = (const float*)d_in[0];   // [N, 128]
    const int*   ei   = (const int*)d_in[1];     // [2, E]
    const float* ev   = (const float*)d_in[2];   // [E]
    const float* w    = (const float*)d_in[3];   // [128, 64]
    const float* bias = (const float*)d_in[4];   // [64]
    float* out = (float*)d_out;                  // [N, 64]

    const int N = in_sizes[0] / DIN;
    const int E = in_sizes[2];
    const int* rows = ei;
    const int* cols = ei + E;
    const int nbuckets = (N + BROWS - 1) / BROWS;   // 391

    // workspace carve-up (256 B aligned)
    char* ws = (char*)d_ws;
    size_t off = 0;
    auto take = [&](size_t bytes) { char* p = ws + off; off = (off + bytes + 255) & ~(size_t)255; return p; };
    unsigned short* support       = (unsigned short*)take((size_t)N * DOUT * sizeof(unsigned short));
    int*            bucket_cnt    = (int*)take((MAXBKT + 1) * sizeof(int));  // [512]=done ticket
    int*            bucket_base   = (int*)take((MAXBKT + 1) * sizeof(int));
    int*            bucket_cursor = (int*)take(MAXBKT * sizeof(int));
    uint2*          tmp           = (uint2*)take((size_t)E * sizeof(uint2));
    (void)ws_size;
    int* done = bucket_cnt + MAXBKT;

    // 1) zero bucket counters + ticket (2 KB)
    hipMemsetAsync(bucket_cnt, 0, (MAXBKT + 1) * sizeof(int), stream);

    // 2) fused GEMM + bucket hist/scan
    int ntiles = N / 16;  // 6250 exact
    gemm_hist_kernel<<<NGEMM + NHIST, 512, 0, stream>>>(x, w, support, ntiles,
                                                        rows, bucket_cnt, bucket_base,
                                                        bucket_cursor, done, E, nbuckets);

    // 3) partition edges into bucket-contiguous tmp
    partition_kernel<<<(E + PART_CHUNK - 1) / PART_CHUNK, PART_BLOCK, 0, stream>>>(
        rows, cols, ev, bucket_cursor, tmp, E);

    // 4) fused single-pass in-LDS row-sort + split-wave pull + bias
    accum_kernel<<<nbuckets, 1024, 0, stream>>>(bucket_base, tmp, support, bias, out, N);
}